// Round 1
// baseline (616.817 us; speedup 1.0000x reference)
//
#include <hip/hip_runtime.h>

// SMPL GAT encoder, fully fused.
// Key insight: with self-loops + tree edges, each destination node has at most
// 2 incoming edges (self + parent) -> the segment softmax is a 2-way softmax.
// One kernel: per-node 3->24 linear+relu, 24->24 linear, attention dots,
// 2-way softmax vs parent, blend, bias, relu.

#define JNT  24      // joints per frame
#define FPB  16      // frames per block
#define TPB  192     // threads per block (8 frames' worth of joints; 2 nodes/thread)
#define NPB  (FPB*JNT)   // 384 nodes per block
#define HSTR 28      // padded LDS row stride for h (+a_src) : 112 B, 16B-aligned

__constant__ int c_par[JNT] = {-1,0,0,0,1,2,3,4,5,6,7,8,9,9,9,12,13,14,16,17,18,19,20,21};

__global__ __launch_bounds__(TPB)
void gat_encoder(const float* __restrict__ src,
                 const float* __restrict__ W_pre,
                 const float* __restrict__ b_pre,
                 const float* __restrict__ W_gat,
                 const float* __restrict__ att_src,
                 const float* __restrict__ att_dst,
                 const float* __restrict__ b_gat,
                 float* __restrict__ out)
{
    __shared__ __align__(16) float s_wpt[JNT*4];     // [k] = {Wp[0][k],Wp[1][k],Wp[2][k],b_pre[k]}
    __shared__ __align__(16) float s_wg[JNT*JNT];    // row-major [k][o]
    __shared__ __align__(16) float s_att[2*JNT];     // att_src(24) | att_dst(24)
    __shared__ __align__(16) float s_bg[JNT];
    __shared__ int s_par[JNT];
    __shared__ __align__(16) float s_src[NPB*3];     // staged input
    __shared__ __align__(16) float s_h[NPB*HSTR];    // per node: h[0..23], a_src[24..26]

    const int tid = threadIdx.x;

    // ---- stage weights / biases / parents ----
    if (tid < JNT) {
        s_wpt[tid*4+0] = W_pre[0*JNT+tid];
        s_wpt[tid*4+1] = W_pre[1*JNT+tid];
        s_wpt[tid*4+2] = W_pre[2*JNT+tid];
        s_wpt[tid*4+3] = b_pre[tid];
        s_par[tid]     = c_par[tid];
    } else if (tid < 48) {
        s_bg[tid-24] = b_gat[tid-24];
    } else if (tid < 72) {
        s_att[tid-48] = att_src[tid-48];
    } else if (tid < 96) {
        s_att[24 + (tid-72)] = att_dst[tid-72];
    }
    #pragma unroll
    for (int i = tid; i < JNT*JNT; i += TPB) s_wg[i] = W_gat[i];

    // ---- stage src (coalesced) ----
    {
        const float* sg = src + (size_t)blockIdx.x * (NPB*3);
        #pragma unroll
        for (int i = tid; i < NPB*3; i += TPB) s_src[i] = sg[i];
    }
    __syncthreads();

    const int f = tid / JNT;          // frame-in-halfblock 0..7
    const int j = tid - f*JNT;        // joint 0..23
    const int par  = s_par[j];
    const int rowA = tid;             // node A local row
    const int rowB = tid + TPB;       // node B local row (frame f+8)

    // ---- x = relu(src*Wp+b) ; h = x*Wg  (incremental, x never stored) ----
    float hA[JNT], hB[JNT];
    #pragma unroll
    for (int o = 0; o < JNT; ++o) { hA[o] = 0.f; hB[o] = 0.f; }

    const float sA0 = s_src[rowA*3+0], sA1 = s_src[rowA*3+1], sA2 = s_src[rowA*3+2];
    const float sB0 = s_src[rowB*3+0], sB1 = s_src[rowB*3+1], sB2 = s_src[rowB*3+2];

    const float4* wpt4 = (const float4*)s_wpt;
    const float4* wg4  = (const float4*)s_wg;

    #pragma unroll
    for (int k = 0; k < JNT; ++k) {
        const float4 wk = wpt4[k];
        const float xA = fmaxf(fmaf(sA0, wk.x, fmaf(sA1, wk.y, fmaf(sA2, wk.z, wk.w))), 0.f);
        const float xB = fmaxf(fmaf(sB0, wk.x, fmaf(sB1, wk.y, fmaf(sB2, wk.z, wk.w))), 0.f);
        #pragma unroll
        for (int o4 = 0; o4 < 6; ++o4) {
            const float4 w = wg4[k*6+o4];
            hA[o4*4+0] = fmaf(xA, w.x, hA[o4*4+0]);
            hA[o4*4+1] = fmaf(xA, w.y, hA[o4*4+1]);
            hA[o4*4+2] = fmaf(xA, w.z, hA[o4*4+2]);
            hA[o4*4+3] = fmaf(xA, w.w, hA[o4*4+3]);
            hB[o4*4+0] = fmaf(xB, w.x, hB[o4*4+0]);
            hB[o4*4+1] = fmaf(xB, w.y, hB[o4*4+1]);
            hB[o4*4+2] = fmaf(xB, w.z, hB[o4*4+2]);
            hB[o4*4+3] = fmaf(xB, w.w, hB[o4*4+3]);
        }
    }

    // ---- attention dots ----
    float asA[3], adA[3], asB[3], adB[3];
    const float4* at4 = (const float4*)s_att;
    #pragma unroll
    for (int hd = 0; hd < 3; ++hd) {
        const float4 a0 = at4[hd*2],   a1 = at4[hd*2+1];
        const float4 d0 = at4[6+hd*2], d1 = at4[6+hd*2+1];
        asA[hd] = hA[hd*8+0]*a0.x + hA[hd*8+1]*a0.y + hA[hd*8+2]*a0.z + hA[hd*8+3]*a0.w
                + hA[hd*8+4]*a1.x + hA[hd*8+5]*a1.y + hA[hd*8+6]*a1.z + hA[hd*8+7]*a1.w;
        adA[hd] = hA[hd*8+0]*d0.x + hA[hd*8+1]*d0.y + hA[hd*8+2]*d0.z + hA[hd*8+3]*d0.w
                + hA[hd*8+4]*d1.x + hA[hd*8+5]*d1.y + hA[hd*8+6]*d1.z + hA[hd*8+7]*d1.w;
        asB[hd] = hB[hd*8+0]*a0.x + hB[hd*8+1]*a0.y + hB[hd*8+2]*a0.z + hB[hd*8+3]*a0.w
                + hB[hd*8+4]*a1.x + hB[hd*8+5]*a1.y + hB[hd*8+6]*a1.z + hB[hd*8+7]*a1.w;
        adB[hd] = hB[hd*8+0]*d0.x + hB[hd*8+1]*d0.y + hB[hd*8+2]*d0.z + hB[hd*8+3]*d0.w
                + hB[hd*8+4]*d1.x + hB[hd*8+5]*d1.y + hB[hd*8+6]*d1.z + hB[hd*8+7]*d1.w;
    }

    // ---- publish h and a_src for children ----
    float* hrA = &s_h[rowA*HSTR];
    float* hrB = &s_h[rowB*HSTR];
    #pragma unroll
    for (int o4 = 0; o4 < 6; ++o4) {
        ((float4*)hrA)[o4] = make_float4(hA[o4*4+0], hA[o4*4+1], hA[o4*4+2], hA[o4*4+3]);
        ((float4*)hrB)[o4] = make_float4(hB[o4*4+0], hB[o4*4+1], hB[o4*4+2], hB[o4*4+3]);
    }
    hrA[24] = asA[0]; hrA[25] = asA[1]; hrA[26] = asA[2];
    hrB[24] = asB[0]; hrB[25] = asB[1]; hrB[26] = asB[2];
    __syncthreads();

    // ---- 2-way softmax vs parent ----
    const int  pj   = (par < 0) ? j : par;     // root: read self, weight forced to 0
    const bool hasp = (par >= 0);
    const float* hpA = &s_h[(f*JNT + pj)*HSTR];
    const float* hpB = hpA + TPB*HSTR;

    float wsA[3], wpA[3], wsB[3], wpB[3];
    #pragma unroll
    for (int hd = 0; hd < 3; ++hd) {
        // node A
        {
            float es = asA[hd] + adA[hd];      es = es < 0.f ? 0.2f*es : es;
            float ep = hpA[24+hd] + adA[hd];   ep = ep < 0.f ? 0.2f*ep : ep;
            float m  = hasp ? fmaxf(es, ep) : es;
            float e1 = __expf(es - m);
            float e2 = hasp ? __expf(ep - m) : 0.f;
            float r  = 1.f / (e1 + e2);
            wsA[hd] = e1*r; wpA[hd] = e2*r;
        }
        // node B
        {
            float es = asB[hd] + adB[hd];      es = es < 0.f ? 0.2f*es : es;
            float ep = hpB[24+hd] + adB[hd];   ep = ep < 0.f ? 0.2f*ep : ep;
            float m  = hasp ? fmaxf(es, ep) : es;
            float e1 = __expf(es - m);
            float e2 = hasp ? __expf(ep - m) : 0.f;
            float r  = 1.f / (e1 + e2);
            wsB[hd] = e1*r; wpB[hd] = e2*r;
        }
    }

    // ---- blend, bias, relu, store ----
    const float4* bg4 = (const float4*)s_bg;
    float* outA = out + ((size_t)blockIdx.x * NPB + rowA) * (size_t)JNT;
    float* outB = out + ((size_t)blockIdx.x * NPB + rowB) * (size_t)JNT;
    #pragma unroll
    for (int o4 = 0; o4 < 6; ++o4) {
        const int hd = o4 >> 1;
        const float4 bg = bg4[o4];
        {
            const float4 p4 = ((const float4*)hpA)[o4];
            float4 r;
            r.x = fmaxf(fmaf(wpA[hd], p4.x, fmaf(wsA[hd], hA[o4*4+0], bg.x)), 0.f);
            r.y = fmaxf(fmaf(wpA[hd], p4.y, fmaf(wsA[hd], hA[o4*4+1], bg.y)), 0.f);
            r.z = fmaxf(fmaf(wpA[hd], p4.z, fmaf(wsA[hd], hA[o4*4+2], bg.z)), 0.f);
            r.w = fmaxf(fmaf(wpA[hd], p4.w, fmaf(wsA[hd], hA[o4*4+3], bg.w)), 0.f);
            ((float4*)outA)[o4] = r;
        }
        {
            const float4 p4 = ((const float4*)hpB)[o4];
            float4 r;
            r.x = fmaxf(fmaf(wpB[hd], p4.x, fmaf(wsB[hd], hB[o4*4+0], bg.x)), 0.f);
            r.y = fmaxf(fmaf(wpB[hd], p4.y, fmaf(wsB[hd], hB[o4*4+1], bg.y)), 0.f);
            r.z = fmaxf(fmaf(wpB[hd], p4.z, fmaf(wsB[hd], hB[o4*4+2], bg.z)), 0.f);
            r.w = fmaxf(fmaf(wpB[hd], p4.w, fmaf(wsB[hd], hB[o4*4+3], bg.w)), 0.f);
            ((float4*)outB)[o4] = r;
        }
    }
}

extern "C" void kernel_launch(void* const* d_in, const int* in_sizes, int n_in,
                              void* d_out, int out_size, void* d_ws, size_t ws_size,
                              hipStream_t stream) {
    const float* src     = (const float*)d_in[0];
    const float* W_pre   = (const float*)d_in[1];
    const float* b_pre   = (const float*)d_in[2];
    const float* W_gat   = (const float*)d_in[3];
    const float* att_src = (const float*)d_in[4];
    const float* att_dst = (const float*)d_in[5];
    const float* b_gat   = (const float*)d_in[6];
    float* out = (float*)d_out;

    const int frames = 64 * 2048;          // N * L
    const int blocks = frames / FPB;       // 8192, exact
    gat_encoder<<<dim3(blocks), dim3(TPB), 0, stream>>>(
        src, W_pre, b_pre, W_gat, att_src, att_dst, b_gat, out);
}

// Round 2
// 401.826 us; speedup vs baseline: 1.5350x; 1.5350x over previous
//
#include <hip/hip_runtime.h>

// SMPL GAT encoder, fully fused, one node per thread.
// Graph insight: self-loops + tree edges => each destination has <=2 in-edges
// (self + parent) => segment softmax is a 2-way softmax.
// All weights are read via wave-uniform global loads (compiler emits s_load ->
// SGPR operands, scalar cache) so the LDS pipe only carries the per-node h
// exchange. LDS ~24 KB, 1 node/thread, 8 frames/block.

#define JNT 24               // joints per frame
#define FPB 8                // frames per block
#define TPB (FPB*JNT)        // 192 threads = 3 waves
#define NPB (FPB*JNT)        // 192 nodes per block (1 per thread)

// SMPL parent table
__constant__ int c_par[JNT] = {-1,0,0,0,1,2,3,4,5,6,7,8,9,9,9,12,13,14,16,17,18,19,20,21};

// swizzled row offset for s_h: stride 28 dwords, +4 dwords every 8 rows.
// Makes the per-lane b128 publish/consume hit distinct 4-bank groups.
__device__ __forceinline__ int hoff(int r) { return r*28 + ((r>>3)<<2); }

#define SH_SIZE 5468   // hoff(NPB-1)+28 = 191*28 + 92 + 28

__global__ __launch_bounds__(TPB, 5)
void gat_encoder(const float* __restrict__ src,
                 const float* __restrict__ W_pre,
                 const float* __restrict__ b_pre,
                 const float* __restrict__ W_gat,
                 const float* __restrict__ att_src,
                 const float* __restrict__ att_dst,
                 const float* __restrict__ b_gat,
                 float* __restrict__ out)
{
    __shared__ float s_src[NPB*3];                 // staged input (coalesced)
    __shared__ int   s_par[JNT];
    __shared__ __align__(16) float s_h[SH_SIZE];   // per node: h[0..23], a_src[24..26]

    const int tid = threadIdx.x;

    if (tid < JNT) s_par[tid] = c_par[tid];
    {
        const float* sg = src + (size_t)blockIdx.x * (NPB*3);
        s_src[tid]         = sg[tid];
        s_src[tid +   TPB] = sg[tid +   TPB];
        s_src[tid + 2*TPB] = sg[tid + 2*TPB];
    }
    __syncthreads();

    const float s0 = s_src[tid*3+0], s1 = s_src[tid*3+1], s2 = s_src[tid*3+2];

    // ---- h = relu(src*W_pre + b_pre) * W_gat, x kept transient ----
    float h[JNT];
    #pragma unroll
    for (int o = 0; o < JNT; ++o) h[o] = 0.f;

    #pragma unroll 2
    for (int k = 0; k < JNT; ++k) {
        // wave-uniform loads -> s_load -> SGPR operands
        const float w0 = W_pre[k], w1 = W_pre[24+k], w2 = W_pre[48+k];
        const float bb = b_pre[k];
        float x = fmaf(s0, w0, fmaf(s1, w1, fmaf(s2, w2, bb)));
        x = fmaxf(x, 0.f);
        #pragma unroll
        for (int o = 0; o < JNT; ++o)
            h[o] = fmaf(x, W_gat[k*JNT + o], h[o]);
    }

    // ---- attention dots (att vectors uniform -> SGPRs) ----
    float as[3], ad[3];
    #pragma unroll
    for (int hd = 0; hd < 3; ++hd) {
        float a = 0.f, d = 0.f;
        #pragma unroll
        for (int o = 0; o < 8; ++o) {
            a = fmaf(h[hd*8+o], att_src[hd*8+o], a);
            d = fmaf(h[hd*8+o], att_dst[hd*8+o], d);
        }
        as[hd] = a; ad[hd] = d;
    }

    // ---- publish h + a_src for children ----
    float* hr = &s_h[hoff(tid)];
    #pragma unroll
    for (int q = 0; q < 6; ++q)
        ((float4*)hr)[q] = make_float4(h[q*4+0], h[q*4+1], h[q*4+2], h[q*4+3]);
    hr[24] = as[0]; hr[25] = as[1]; hr[26] = as[2];
    __syncthreads();

    // ---- 2-way softmax vs parent ----
    const int  f    = tid / JNT;
    const int  j    = tid - f*JNT;
    const int  par  = s_par[j];
    const bool hasp = (par >= 0);
    const float* hp = &s_h[hoff(f*JNT + (hasp ? par : j))];

    float ws[3], wpv[3];
    #pragma unroll
    for (int hd = 0; hd < 3; ++hd) {
        float es = as[hd] + ad[hd];      es = es < 0.f ? 0.2f*es : es;
        float ep = hp[24+hd] + ad[hd];   ep = ep < 0.f ? 0.2f*ep : ep;
        float m  = hasp ? fmaxf(es, ep) : es;
        float e1 = __expf(es - m);
        float e2 = hasp ? __expf(ep - m) : 0.f;
        float r  = 1.f / (e1 + e2);
        ws[hd] = e1*r; wpv[hd] = e2*r;
    }

    // ---- blend, bias (uniform), relu, store ----
    float* op = out + ((size_t)blockIdx.x * NPB + tid) * (size_t)JNT;
    #pragma unroll
    for (int q = 0; q < 6; ++q) {
        const int hd = q >> 1;
        const float4 p4 = ((const float4*)hp)[q];
        float4 r;
        r.x = fmaxf(fmaf(wpv[hd], p4.x, fmaf(ws[hd], h[q*4+0], b_gat[q*4+0])), 0.f);
        r.y = fmaxf(fmaf(wpv[hd], p4.y, fmaf(ws[hd], h[q*4+1], b_gat[q*4+1])), 0.f);
        r.z = fmaxf(fmaf(wpv[hd], p4.z, fmaf(ws[hd], h[q*4+2], b_gat[q*4+2])), 0.f);
        r.w = fmaxf(fmaf(wpv[hd], p4.w, fmaf(ws[hd], h[q*4+3], b_gat[q*4+3])), 0.f);
        ((float4*)op)[q] = r;
    }
}

extern "C" void kernel_launch(void* const* d_in, const int* in_sizes, int n_in,
                              void* d_out, int out_size, void* d_ws, size_t ws_size,
                              hipStream_t stream) {
    const float* src     = (const float*)d_in[0];
    const float* W_pre   = (const float*)d_in[1];
    const float* b_pre   = (const float*)d_in[2];
    const float* W_gat   = (const float*)d_in[3];
    const float* att_src = (const float*)d_in[4];
    const float* att_dst = (const float*)d_in[5];
    const float* b_gat   = (const float*)d_in[6];
    float* out = (float*)d_out;

    const int frames = 64 * 2048;        // N * L
    const int blocks = frames / FPB;     // 16384, exact
    gat_encoder<<<dim3(blocks), dim3(TPB), 0, stream>>>(
        src, W_pre, b_pre, W_gat, att_src, att_dst, b_gat, out);
}